// Round 4
// baseline (1087.934 us; speedup 1.0000x reference)
//
#include <hip/hip_runtime.h>
#include <hip/hip_bf16.h>

// Lightning attention, B=2 H=16 N=4096 D=128, BLOCK=128, nb=32.
// Single fused kernel: grid = 32 (b,h) chains x 16 groups of 2 chunks.
// Phase 1: per-group decay-weighted KV sum (MFMA) + stage v^T (bf16) to ws.
// Chain:   publish/wait group-start states via device atomics (all blocks resident).
// Phase 3: per chunk: scores(global q,k) -> P; o_inter = q@S^T(LDS); KV recompute
//          (k re-read, L3-hot); S^T update in LDS; o += P@v (v^T from ws); store.

#define LDB   136   // LDS row stride in u16 (272B, 16B-aligned)
#define NB    32    // chunks
#define NG    16    // groups per (b,h)
#define CPG   2     // chunks per group
#define HH    16
#define NSEQ  4096

typedef float  f32x4  __attribute__((ext_vector_type(4)));
typedef __bf16 bf16x8 __attribute__((ext_vector_type(8)));
typedef unsigned short u16x8 __attribute__((ext_vector_type(8)));
typedef unsigned short u16x4 __attribute__((ext_vector_type(4)));

__device__ __forceinline__ unsigned short f2bf(float f) {
  unsigned int u = __float_as_uint(f);
  unsigned int r = (u + 0x7fffu + ((u >> 16) & 1u)) >> 16;
  return (unsigned short)r;
}
__device__ __forceinline__ float bf2f(unsigned short h) {
  return __uint_as_float(((unsigned int)h) << 16);
}
__device__ __forceinline__ bf16x8 cvt8(float4 a, float4 b) {
  bf16x8 r;
  r[0] = (__bf16)a.x; r[1] = (__bf16)a.y; r[2] = (__bf16)a.z; r[3] = (__bf16)a.w;
  r[4] = (__bf16)b.x; r[5] = (__bf16)b.y; r[6] = (__bf16)b.z; r[7] = (__bf16)b.w;
  return r;
}

// 128x128 fp32 row-major [tau][d] -> LDS bf16 transposed [d][LDB], 512 threads.
__device__ __forceinline__ void stage_transpose512(const float* __restrict__ src,
                                                   unsigned short* dst, int tid) {
#pragma unroll
  for (int i = 0; i < 8; ++i) {
    int idx = i * 512 + tid;
    int d   = idx & 127;
    int tq  = idx >> 7;
    u16x4 w;
#pragma unroll
    for (int j = 0; j < 4; ++j)
      w[j] = f2bf(src[(tq * 4 + j) * 128 + d]);
    *reinterpret_cast<u16x4*>(dst + d * LDB + tq * 4) = w;
  }
}

// Same + scale column tau by exp(-sl*(128-tau))  (k_decay).
__device__ __forceinline__ void stage_transpose_scaled512(const float* __restrict__ src,
                                                          unsigned short* dst, int tid,
                                                          float sl) {
#pragma unroll
  for (int i = 0; i < 8; ++i) {
    int idx = i * 512 + tid;
    int d   = idx & 127;
    int tq  = idx >> 7;
    u16x4 w;
#pragma unroll
    for (int j = 0; j < 4; ++j) {
      int tau = tq * 4 + j;
      float kd = __expf(-sl * (float)(128 - tau));
      w[j] = f2bf(src[tau * 128 + d] * kd);
    }
    *reinterpret_cast<u16x4*>(dst + d * LDB + tq * 4) = w;
  }
}

// D += A*B from LDS (BT = B^T row-major in LDS). Wave tile: M*16 x 64 at (wr,wc).
template <int M>
__device__ __forceinline__ void mmT(const unsigned short* A, const unsigned short* BT,
                                    int lane, int wr, int wc, f32x4 acc[M][4]) {
  const int lr = lane & 15;
  const int lg = lane >> 4;
#pragma unroll
  for (int kk = 0; kk < 4; ++kk) {
    const int kb = kk * 32 + lg * 8;
    bf16x8 af[M], bf_[4];
#pragma unroll
    for (int m = 0; m < M; ++m) {
      u16x8 raw = *reinterpret_cast<const u16x8*>(A + (wr + m * 16 + lr) * LDB + kb);
      af[m] = __builtin_bit_cast(bf16x8, raw);
    }
#pragma unroll
    for (int n = 0; n < 4; ++n) {
      u16x8 raw = *reinterpret_cast<const u16x8*>(BT + (wc + n * 16 + lr) * LDB + kb);
      bf_[n] = __builtin_bit_cast(bf16x8, raw);
    }
#pragma unroll
    for (int m = 0; m < M; ++m)
#pragma unroll
      for (int n = 0; n < 4; ++n)
        acc[m][n] = __builtin_amdgcn_mfma_f32_16x16x32_bf16(af[m], bf_[n], acc[m][n], 0, 0, 0);
  }
}

__global__ void la_zero(unsigned int* __restrict__ flags) {
  if (threadIdx.x < 32) flags[threadIdx.x] = 0u;
}

__global__ __launch_bounds__(512, 4) void la_fused(const float* __restrict__ q,
                                                   const float* __restrict__ k,
                                                   const float* __restrict__ v,
                                                   const float* __restrict__ s,
                                                   unsigned short* __restrict__ ws,
                                                   float* __restrict__ out) {
  __shared__ __align__(16) unsigned short buf0[128 * LDB];  // kT / P
  __shared__ __align__(16) unsigned short buf1[128 * LDB];  // vT (ph1) / S^T (ph3)

  const int tid = threadIdx.x;
  const int bid = blockIdx.x;
  const int g   = bid & (NG - 1);
  const int bh  = bid >> 4;
  const float sl  = s[bh & (HH - 1)];
  const float bd  = __expf(-sl * 128.f);      // per-chunk state decay
  const float bdg = bd * bd;                  // per-group (CPG=2)

  unsigned short* vtws = ws;                                        // 32 MB bf16
  unsigned short* sws  = ws + (size_t)32 * NB * 16384;              // 16 MB bf16
  unsigned int*   flags = (unsigned int*)(sws + (size_t)32 * NG * 16384);

  const int wid = tid >> 6, lane = tid & 63;
  const int wr = (wid >> 1) * 32, wc = (wid & 1) * 64;
  const int lr = lane & 15, lg = lane >> 4;
  const int c0 = g * CPG;

  // ---------- phase 1: local group KV sum, stage v^T to ws ----------
  f32x4 acc[2][4];
#pragma unroll
  for (int m = 0; m < 2; ++m)
#pragma unroll
    for (int n = 0; n < 4; ++n)
      acc[m][n] = (f32x4)0.f;

#pragma unroll
  for (int j = 0; j < CPG; ++j) {
    const int c = c0 + j;
    const size_t base = ((size_t)bh * NSEQ + (size_t)c * 128) * 128;
    stage_transpose_scaled512(k + base, buf0, tid, sl);
    stage_transpose512(v + base, buf1, tid);
    __syncthreads();
    if (j > 0) {
#pragma unroll
      for (int m = 0; m < 2; ++m)
#pragma unroll
        for (int n = 0; n < 4; ++n)
          acc[m][n] *= bd;
    }
    mmT<2>(buf1, buf0, lane, wr, wc, acc);   // KV^T += v^T @ (k*kd)
    // copy v^T LDS -> ws (coalesced)
    unsigned short* vdst = vtws + ((size_t)bh * NB + c) * 16384;
#pragma unroll
    for (int i = 0; i < 4; ++i) {
      int linear = (i * 512 + tid) * 8;
      int r = linear >> 7, cc = linear & 127;
      *reinterpret_cast<u16x8*>(vdst + linear) =
          *reinterpret_cast<const u16x8*>(buf1 + r * LDB + cc);
    }
    __syncthreads();
  }

  __threadfence();  // release v^T + prepare for chain

  // ---------- chain: wait for group-start state, publish inclusive ----------
  unsigned int* flag = flags + bh;
  if (g > 0) {
    if (tid == 0) {
      int guard = 0;
      while (atomicAdd(flag, 0u) < (unsigned int)g) {
        __builtin_amdgcn_s_sleep(8);
        if (++guard > (1 << 26)) break;  // safety net: fail visibly, not hang
      }
    }
    __syncthreads();
    __threadfence();  // acquire: invalidate L1 before reading sws/vtws
  }

  // load S_g (or zeros) into buf1 as S^T rows [e][LDB]
  {
    const unsigned short* ssrc = sws + ((size_t)bh * NG + g) * 16384;
#pragma unroll
    for (int i = 0; i < 4; ++i) {
      int linear = (i * 512 + tid) * 8;
      int r = linear >> 7, cc = linear & 127;
      u16x8 w;
      if (g == 0) w = (u16x8)(unsigned short)0;
      else        w = *reinterpret_cast<const u16x8*>(ssrc + linear);
      *reinterpret_cast<u16x8*>(buf1 + r * LDB + cc) = w;
    }
  }
  __syncthreads();

  if (g < NG - 1) {
    unsigned short* sdst = sws + ((size_t)bh * NG + (g + 1)) * 16384;
#pragma unroll
    for (int m = 0; m < 2; ++m)
#pragma unroll
      for (int n = 0; n < 4; ++n)
#pragma unroll
        for (int r = 0; r < 4; ++r) {
          int e = wr + m * 16 + lg * 4 + r;
          int d = wc + n * 16 + lr;
          float val = bdg * bf2f(buf1[e * LDB + d]) + acc[m][n][r];
          sdst[e * 128 + d] = f2bf(val);
        }
    __threadfence();
    __syncthreads();
    if (tid == 0) atomicAdd(flag, 1u);
  }

  // ---------- phase 3: outputs, 2 chunks sequentially ----------
#pragma unroll
  for (int j = 0; j < CPG; ++j) {
    const int c = c0 + j;
    const size_t base = ((size_t)bh * NSEQ + (size_t)c * 128) * 128;
    const unsigned short* vch = vtws + ((size_t)bh * NB + c) * 16384;

    __syncthreads();                       // buf0 free for restaging
    stage_transpose_scaled512(k + base, buf0, tid, sl);   // kT*kd (L3-hot re-read)

    // scores = q @ k^T (both from global fp32)
    f32x4 accS[2][4];
#pragma unroll
    for (int m = 0; m < 2; ++m)
#pragma unroll
      for (int n = 0; n < 4; ++n)
        accS[m][n] = (f32x4)0.f;

    bf16x8 qf[4][2];
#pragma unroll
    for (int kk = 0; kk < 4; ++kk) {
      const int kb = kk * 32 + lg * 8;
#pragma unroll
      for (int m = 0; m < 2; ++m) {
        const float* p = q + base + (size_t)(wr + m * 16 + lr) * 128 + kb;
        qf[kk][m] = cvt8(*reinterpret_cast<const float4*>(p),
                         *reinterpret_cast<const float4*>(p + 4));
      }
      bf16x8 kf[4];
#pragma unroll
      for (int n = 0; n < 4; ++n) {
        const float* p = k + base + (size_t)(wc + n * 16 + lr) * 128 + kb;
        kf[n] = cvt8(*reinterpret_cast<const float4*>(p),
                     *reinterpret_cast<const float4*>(p + 4));
      }
#pragma unroll
      for (int m = 0; m < 2; ++m)
#pragma unroll
        for (int n = 0; n < 4; ++n)
          accS[m][n] = __builtin_amdgcn_mfma_f32_16x16x32_bf16(qf[kk][m], kf[n], accS[m][n], 0, 0, 0);
    }
    __syncthreads();                       // kT staged

    // o_inter = q @ S^T (LDS buf1)
    f32x4 oi[2][4];
#pragma unroll
    for (int m = 0; m < 2; ++m)
#pragma unroll
      for (int n = 0; n < 4; ++n)
        oi[m][n] = (f32x4)0.f;
#pragma unroll
    for (int kk = 0; kk < 4; ++kk) {
      const int kb = kk * 32 + lg * 8;
      bf16x8 sf[4];
#pragma unroll
      for (int n = 0; n < 4; ++n) {
        u16x8 raw = *reinterpret_cast<const u16x8*>(buf1 + (wc + n * 16 + lr) * LDB + kb);
        sf[n] = __builtin_bit_cast(bf16x8, raw);
      }
#pragma unroll
      for (int m = 0; m < 2; ++m)
#pragma unroll
        for (int n = 0; n < 4; ++n)
          oi[m][n] = __builtin_amdgcn_mfma_f32_16x16x32_bf16(qf[kk][m], sf[n], oi[m][n], 0, 0, 0);
    }

    // kv = KV^T: A-frags v^T from ws(global), BT-frags kT from LDS
#pragma unroll
    for (int m = 0; m < 2; ++m)
#pragma unroll
      for (int n = 0; n < 4; ++n)
        acc[m][n] = (f32x4)0.f;
#pragma unroll
    for (int kk = 0; kk < 4; ++kk) {
      const int kb = kk * 32 + lg * 8;
      bf16x8 va[2];
#pragma unroll
      for (int m = 0; m < 2; ++m) {
        u16x8 raw = *reinterpret_cast<const u16x8*>(vch + (size_t)(wr + m * 16 + lr) * 128 + kb);
        va[m] = __builtin_bit_cast(bf16x8, raw);
      }
      bf16x8 kb_[4];
#pragma unroll
      for (int n = 0; n < 4; ++n) {
        u16x8 raw = *reinterpret_cast<const u16x8*>(buf0 + (wc + n * 16 + lr) * LDB + kb);
        kb_[n] = __builtin_bit_cast(bf16x8, raw);
      }
#pragma unroll
      for (int m = 0; m < 2; ++m)
#pragma unroll
        for (int n = 0; n < 4; ++n)
          acc[m][n] = __builtin_amdgcn_mfma_f32_16x16x32_bf16(va[m], kb_[n], acc[m][n], 0, 0, 0);
    }
    __syncthreads();                       // kT + S^T consumed

    // P -> buf0 (over kT); scale oi by q_decay; update S^T (except last chunk)
#pragma unroll
    for (int m = 0; m < 2; ++m)
#pragma unroll
      for (int n = 0; n < 4; ++n)
#pragma unroll
        for (int r = 0; r < 4; ++r) {
          int t  = wr + m * 16 + lg * 4 + r;
          int sc = wc + n * 16 + lr;
          float pv = (t >= sc) ? accS[m][n][r] * __expf(-sl * (float)(t - sc)) : 0.f;
          buf0[t * LDB + sc] = f2bf(pv);
        }
#pragma unroll
    for (int m = 0; m < 2; ++m)
#pragma unroll
      for (int r = 0; r < 4; ++r) {
        float qd = __expf(-sl * (float)(wr + m * 16 + lg * 4 + r));
#pragma unroll
        for (int n = 0; n < 4; ++n)
          oi[m][n][r] *= qd;
      }
    if (j < CPG - 1) {
#pragma unroll
      for (int m = 0; m < 2; ++m)
#pragma unroll
        for (int n = 0; n < 4; ++n)
#pragma unroll
          for (int r = 0; r < 4; ++r) {
            int e = wr + m * 16 + lg * 4 + r;
            int d = wc + n * 16 + lr;
            buf1[e * LDB + d] = f2bf(bd * bf2f(buf1[e * LDB + d]) + acc[m][n][r]);
          }
    }
    __syncthreads();                       // P ready (+ S^T updated)

    // o = P @ v + oi   (v^T B-frags from ws global)
#pragma unroll
    for (int kk = 0; kk < 4; ++kk) {
      const int kb = kk * 32 + lg * 8;
      bf16x8 pa[2];
#pragma unroll
      for (int m = 0; m < 2; ++m) {
        u16x8 raw = *reinterpret_cast<const u16x8*>(buf0 + (wr + m * 16 + lr) * LDB + kb);
        pa[m] = __builtin_bit_cast(bf16x8, raw);
      }
      bf16x8 vb[4];
#pragma unroll
      for (int n = 0; n < 4; ++n) {
        u16x8 raw = *reinterpret_cast<const u16x8*>(vch + (size_t)(wc + n * 16 + lr) * 128 + kb);
        vb[n] = __builtin_bit_cast(bf16x8, raw);
      }
#pragma unroll
      for (int m = 0; m < 2; ++m)
#pragma unroll
        for (int n = 0; n < 4; ++n)
          oi[m][n] = __builtin_amdgcn_mfma_f32_16x16x32_bf16(pa[m], vb[n], oi[m][n], 0, 0, 0);
    }

#pragma unroll
    for (int m = 0; m < 2; ++m)
#pragma unroll
      for (int n = 0; n < 4; ++n)
#pragma unroll
        for (int r = 0; r < 4; ++r)
          __builtin_nontemporal_store(oi[m][n][r],
              out + base + (size_t)(wr + m * 16 + lg * 4 + r) * 128 + (wc + n * 16 + lr));
  }
}

extern "C" void kernel_launch(void* const* d_in, const int* in_sizes, int n_in,
                              void* d_out, int out_size, void* d_ws, size_t ws_size,
                              hipStream_t stream) {
  const float* q = (const float*)d_in[0];
  const float* k = (const float*)d_in[1];
  const float* v = (const float*)d_in[2];
  const float* s = (const float*)d_in[3];
  float* out = (float*)d_out;
  unsigned short* ws = (unsigned short*)d_ws;  // ~48 MB used

  unsigned short* sws = ws + (size_t)32 * NB * 16384;
  unsigned int* flags = (unsigned int*)(sws + (size_t)32 * NG * 16384);

  la_zero<<<dim3(1), dim3(64), 0, stream>>>(flags);
  la_fused<<<dim3(32 * NG), dim3(512), 0, stream>>>(q, k, v, s, ws, out);
}

// Round 5
// 140.358 us; speedup vs baseline: 7.7512x; 7.7512x over previous
//
#include <hip/hip_runtime.h>
#include <hip/hip_bf16.h>

// Lightning attention, B=2 H=16 N=4096 D=128, BLOCK=128, nb=32.
// Pass 1 (la_kv):   per-chunk KV^T (bf16) -> ws; also dump v^T (bf16) -> ws. [512 thr]
// Pass 2 (la_scan): in-place decay scan over chunks (x4 vec).                [256 thr]
// Pass 3 (la_out):  out = (q@k^T * intra)@v + diag(q_decay)*(q@S).           [256 thr]
//   Wave tile 32x128: P stays wave-private (own LDS strip) -> ZERO barriers,
//   one 34KB LDS buffer -> 4 blocks/CU. q,k,S,vT fragments straight from global.

#define LDB   136   // LDS row stride in u16 (272B, 16B-aligned; 2-way conflict = free)
#define NB    32
#define NG    16
#define HH    16
#define NSEQ  4096

typedef float  f32x4  __attribute__((ext_vector_type(4)));
typedef __bf16 bf16x8 __attribute__((ext_vector_type(8)));
typedef unsigned short u16x8 __attribute__((ext_vector_type(8)));
typedef unsigned short u16x4 __attribute__((ext_vector_type(4)));

__device__ __forceinline__ unsigned short f2bf(float f) {
  unsigned int u = __float_as_uint(f);
  unsigned int r = (u + 0x7fffu + ((u >> 16) & 1u)) >> 16;
  return (unsigned short)r;
}
__device__ __forceinline__ float bf2f(unsigned short h) {
  return __uint_as_float(((unsigned int)h) << 16);
}
__device__ __forceinline__ bf16x8 cvt8(float4 a, float4 b) {
  bf16x8 r;
  r[0] = (__bf16)a.x; r[1] = (__bf16)a.y; r[2] = (__bf16)a.z; r[3] = (__bf16)a.w;
  r[4] = (__bf16)b.x; r[5] = (__bf16)b.y; r[6] = (__bf16)b.z; r[7] = (__bf16)b.w;
  return r;
}

// 128x128 fp32 row-major [tau][d] -> LDS bf16 transposed [d][LDB], 512 threads.
__device__ __forceinline__ void stage_transpose512(const float* __restrict__ src,
                                                   unsigned short* dst, int tid) {
#pragma unroll
  for (int i = 0; i < 8; ++i) {
    int idx = i * 512 + tid;
    int d   = idx & 127;
    int tq  = idx >> 7;
    u16x4 w;
#pragma unroll
    for (int j = 0; j < 4; ++j)
      w[j] = f2bf(src[(tq * 4 + j) * 128 + d]);
    *reinterpret_cast<u16x4*>(dst + d * LDB + tq * 4) = w;
  }
}

// Same + scale column tau by exp(-sl*(128-tau))  (k_decay).
__device__ __forceinline__ void stage_transpose_scaled512(const float* __restrict__ src,
                                                          unsigned short* dst, int tid,
                                                          float sl) {
#pragma unroll
  for (int i = 0; i < 8; ++i) {
    int idx = i * 512 + tid;
    int d   = idx & 127;
    int tq  = idx >> 7;
    u16x4 w;
#pragma unroll
    for (int j = 0; j < 4; ++j) {
      int tau = tq * 4 + j;
      float kd = __expf(-sl * (float)(128 - tau));
      w[j] = f2bf(src[tau * 128 + d] * kd);
    }
    *reinterpret_cast<u16x4*>(dst + d * LDB + tq * 4) = w;
  }
}

// Pass 1: KVT_c[e][d] = sum_tau v[tau][e]*k[tau][d]*kd(tau) -> kvws; v^T -> vtws.
__global__ __launch_bounds__(512, 4) void la_kv(const float* __restrict__ k,
                                                const float* __restrict__ v,
                                                const float* __restrict__ s,
                                                unsigned short* __restrict__ vtws,
                                                unsigned short* __restrict__ kvws) {
  __shared__ __align__(16) unsigned short kTs[128 * LDB];
  __shared__ __align__(16) unsigned short vT[128 * LDB];
  const int tid = threadIdx.x;
  const int bid = blockIdx.x;
  const int c   = bid & (NB - 1);
  const int bh  = bid >> 5;
  const float sl = s[bh & (HH - 1)];
  const size_t base = ((size_t)bh * NSEQ + (size_t)c * 128) * 128;

  stage_transpose_scaled512(k + base, kTs, tid, sl);
  stage_transpose512(v + base, vT, tid);
  __syncthreads();

  const int wid = tid >> 6, lane = tid & 63;
  const int wr = (wid >> 1) * 32, wc = (wid & 1) * 64;
  const int lr = lane & 15, lg = lane >> 4;

  f32x4 acc[2][4];
#pragma unroll
  for (int m = 0; m < 2; ++m)
#pragma unroll
    for (int n = 0; n < 4; ++n)
      acc[m][n] = (f32x4)0.f;

  // KV^T += v^T @ (k*kd): A = vT[e][tau], BT = kTs[d][tau]
#pragma unroll
  for (int kk = 0; kk < 4; ++kk) {
    const int kb = kk * 32 + lg * 8;
    bf16x8 af[2], bf_[4];
#pragma unroll
    for (int m = 0; m < 2; ++m)
      af[m] = __builtin_bit_cast(bf16x8,
          *reinterpret_cast<const u16x8*>(vT + (wr + m * 16 + lr) * LDB + kb));
#pragma unroll
    for (int n = 0; n < 4; ++n)
      bf_[n] = __builtin_bit_cast(bf16x8,
          *reinterpret_cast<const u16x8*>(kTs + (wc + n * 16 + lr) * LDB + kb));
#pragma unroll
    for (int m = 0; m < 2; ++m)
#pragma unroll
      for (int n = 0; n < 4; ++n)
        acc[m][n] = __builtin_amdgcn_mfma_f32_16x16x32_bf16(af[m], bf_[n], acc[m][n], 0, 0, 0);
  }

  unsigned short* dst = kvws + ((size_t)bh * NB + c) * 16384;
#pragma unroll
  for (int m = 0; m < 2; ++m)
#pragma unroll
    for (int n = 0; n < 4; ++n)
#pragma unroll
      for (int r = 0; r < 4; ++r)
        dst[(wr + m * 16 + lg * 4 + r) * 128 + (wc + n * 16 + lr)] = f2bf(acc[m][n][r]);

  // dump v^T (coalesced 16B)
  unsigned short* vdst = vtws + ((size_t)bh * NB + c) * 16384;
#pragma unroll
  for (int i = 0; i < 4; ++i) {
    int linear = (i * 512 + tid) * 8;
    int r = linear >> 7, cc = linear & 127;
    *reinterpret_cast<u16x8*>(vdst + linear) =
        *reinterpret_cast<const u16x8*>(vT + r * LDB + cc);
  }
}

// Pass 2: in-place decay scan, 4 elements per thread. After: kvws[c] = S^T at chunk start.
__global__ __launch_bounds__(256) void la_scan(const float* __restrict__ s,
                                               unsigned short* __restrict__ kvws) {
  const int t   = blockIdx.x * 256 + threadIdx.x;
  const int bh  = t >> 12;
  const int de4 = (t & 4095) * 4;
  const float bd = __expf(-s[bh & (HH - 1)] * 128.f);
  unsigned short* p = kvws + (size_t)bh * NB * 16384 + de4;
  float st[4] = {0.f, 0.f, 0.f, 0.f};
#pragma unroll
  for (int c = 0; c < NB; ++c) {
    u16x4 w = *reinterpret_cast<u16x4*>(p + c * 16384);
    u16x4 o;
#pragma unroll
    for (int j = 0; j < 4; ++j) {
      float tmp = bf2f(w[j]);
      o[j] = f2bf(st[j]);
      st[j] = st[j] * bd + tmp;
    }
    *reinterpret_cast<u16x4*>(p + c * 16384) = o;
  }
}

// Pass 3: wave-private 32x128 tiles, zero barriers.
__global__ __launch_bounds__(256, 4) void la_out(const float* __restrict__ q,
                                                 const float* __restrict__ k,
                                                 const float* __restrict__ s,
                                                 const unsigned short* __restrict__ vtws,
                                                 const unsigned short* __restrict__ kvws,
                                                 float* __restrict__ out) {
  __shared__ __align__(16) unsigned short Pb[128 * LDB];
  const int tid = threadIdx.x;
  const int bid = blockIdx.x;
  const int c   = bid & (NB - 1);
  const int bh  = bid >> 5;
  const float sl = s[bh & (HH - 1)];
  const size_t base = ((size_t)bh * NSEQ + (size_t)c * 128) * 128;

  const int wid = tid >> 6, lane = tid & 63;
  const int wr = wid * 32;                 // wave owns rows wr..wr+31, all 128 cols
  const int lr = lane & 15, lg = lane >> 4;

  const unsigned short* vch = vtws + ((size_t)bh * NB + c) * 16384;
  const unsigned short* Sp  = kvws + ((size_t)bh * NB + c) * 16384;

  // ---- scores = q @ k^T (fragments straight from global fp32) ----
  f32x4 accS[2][8];
#pragma unroll
  for (int m = 0; m < 2; ++m)
#pragma unroll
    for (int n = 0; n < 8; ++n)
      accS[m][n] = (f32x4)0.f;

  bf16x8 qf[4][2];  // kept live for q@S
#pragma unroll
  for (int kk = 0; kk < 4; ++kk) {
    const int kb = kk * 32 + lg * 8;
#pragma unroll
    for (int m = 0; m < 2; ++m) {
      const float* p = q + base + (size_t)(wr + m * 16 + lr) * 128 + kb;
      qf[kk][m] = cvt8(*reinterpret_cast<const float4*>(p),
                       *reinterpret_cast<const float4*>(p + 4));
    }
#pragma unroll
    for (int n = 0; n < 8; ++n) {
      const float* p = k + base + (size_t)(n * 16 + lr) * 128 + kb;
      bf16x8 kf = cvt8(*reinterpret_cast<const float4*>(p),
                       *reinterpret_cast<const float4*>(p + 4));
#pragma unroll
      for (int m = 0; m < 2; ++m)
        accS[m][n] = __builtin_amdgcn_mfma_f32_16x16x32_bf16(qf[kk][m], kf, accS[m][n], 0, 0, 0);
    }
  }

  // ---- P = scores * intra_decay (causal) -> own LDS strip (no barrier) ----
#pragma unroll
  for (int m = 0; m < 2; ++m)
#pragma unroll
    for (int n = 0; n < 8; ++n)
#pragma unroll
      for (int r = 0; r < 4; ++r) {
        int t  = wr + m * 16 + lg * 4 + r;
        int sc = n * 16 + lr;
        float pv = (t >= sc) ? accS[m][n][r] * __expf(-sl * (float)(t - sc)) : 0.f;
        Pb[t * LDB + sc] = f2bf(pv);
      }

  // ---- oi = q @ S (S^T fragments from global bf16 ws) ----
  f32x4 oi[2][8];
#pragma unroll
  for (int m = 0; m < 2; ++m)
#pragma unroll
    for (int n = 0; n < 8; ++n)
      oi[m][n] = (f32x4)0.f;

#pragma unroll
  for (int kk = 0; kk < 4; ++kk) {
    const int kb = kk * 32 + lg * 8;
#pragma unroll
    for (int n = 0; n < 8; ++n) {
      bf16x8 sf = __builtin_bit_cast(bf16x8,
          *reinterpret_cast<const u16x8*>(Sp + (size_t)(n * 16 + lr) * 128 + kb));
#pragma unroll
      for (int m = 0; m < 2; ++m)
        oi[m][n] = __builtin_amdgcn_mfma_f32_16x16x32_bf16(qf[kk][m], sf, oi[m][n], 0, 0, 0);
    }
  }

  // row-scale by q_decay
#pragma unroll
  for (int m = 0; m < 2; ++m)
#pragma unroll
    for (int r = 0; r < 4; ++r) {
      float qd = __expf(-sl * (float)(wr + m * 16 + lg * 4 + r));
#pragma unroll
      for (int n = 0; n < 8; ++n)
        oi[m][n][r] *= qd;
    }

  // ---- oi += P @ v  (P from own LDS strip, v^T fragments from global ws) ----
#pragma unroll
  for (int kk = 0; kk < 4; ++kk) {
    const int kb = kk * 32 + lg * 8;
    bf16x8 pa[2];
#pragma unroll
    for (int m = 0; m < 2; ++m)
      pa[m] = __builtin_bit_cast(bf16x8,
          *reinterpret_cast<const u16x8*>(Pb + (wr + m * 16 + lr) * LDB + kb));
#pragma unroll
    for (int n = 0; n < 8; ++n) {
      bf16x8 vb = __builtin_bit_cast(bf16x8,
          *reinterpret_cast<const u16x8*>(vch + (size_t)(n * 16 + lr) * 128 + kb));
#pragma unroll
      for (int m = 0; m < 2; ++m)
        oi[m][n] = __builtin_amdgcn_mfma_f32_16x16x32_bf16(pa[m], vb, oi[m][n], 0, 0, 0);
    }
  }

#pragma unroll
  for (int m = 0; m < 2; ++m)
#pragma unroll
    for (int n = 0; n < 8; ++n)
#pragma unroll
      for (int r = 0; r < 4; ++r)
        __builtin_nontemporal_store(oi[m][n][r],
            out + base + (size_t)(wr + m * 16 + lg * 4 + r) * 128 + (n * 16 + lr));
}

extern "C" void kernel_launch(void* const* d_in, const int* in_sizes, int n_in,
                              void* d_out, int out_size, void* d_ws, size_t ws_size,
                              hipStream_t stream) {
  const float* q = (const float*)d_in[0];
  const float* k = (const float*)d_in[1];
  const float* v = (const float*)d_in[2];
  const float* s = (const float*)d_in[3];
  float* out = (float*)d_out;
  unsigned short* vtws = (unsigned short*)d_ws;                       // 32 MiB
  unsigned short* kvws = vtws + (size_t)32 * NB * 16384;              // 32 MiB

  la_kv<<<dim3(2 * HH * NB), dim3(512), 0, stream>>>(k, v, s, vtws, kvws);
  la_scan<<<dim3(2 * HH * 16384 / 4 / 256), dim3(256), 0, stream>>>(s, kvws);
  la_out<<<dim3(2 * HH * NB), dim3(256), 0, stream>>>(q, k, s, vtws, kvws, out);
}